// Round 1
// baseline (862.023 us; speedup 1.0000x reference)
//
#include <hip/hip_runtime.h>
#include <hip/hip_bf16.h>

typedef __bf16 bf16x8 __attribute__((ext_vector_type(8)));
typedef float  f32x4  __attribute__((ext_vector_type(4)));

#define MFMA16(a, b, c) __builtin_amdgcn_mfma_f32_16x16x32_bf16(a, b, c, 0, 0, 0)

// async global->LDS, 16 B per lane. LDS dest is wave-uniform base + lane*16;
// the GLOBAL address is per-lane free — we exploit that for the XOR swizzle.
__device__ __forceinline__ void async16(const __bf16* g, __bf16* l) {
    __builtin_amdgcn_global_load_lds(
        (const __attribute__((address_space(1))) unsigned int*)g,
        (__attribute__((address_space(3))) unsigned int*)l, 16, 0, 0);
}

// B=8 T=192 N=64 D=512 H=8 DH=64 C=8 ; per-n GEMM rows M = B*T = 1536
// LDS tiles use XOR chunk swizzle: LDS[row][chunk c] = global chunk c ^ (row&7)
// so b128 fragment reads spread over all 32 banks (2 lanes/group = free).

// ---------------------------------------------------------------------------
__global__ void k_cast3(const float* __restrict__ wq, const float* __restrict__ wv,
                        const float* __restrict__ wp,
                        __bf16* __restrict__ oq, __bf16* __restrict__ ov,
                        __bf16* __restrict__ op) {
    int i = blockIdx.x * 256 + threadIdx.x;
    oq[i] = (__bf16)wq[i];
    ov[i] = (__bf16)wv[i];
    op[i] = (__bf16)wp[i];
}

// Wk [c][d][e] fp32 -> bf16 [c][e][d]
__global__ void k_twk(const float* __restrict__ wk, __bf16* __restrict__ o) {
    int i = blockIdx.x * 256 + threadIdx.x;
    int c = i >> 18;
    int r = i & 262143;
    int d = r >> 9;
    int e = r & 511;
    o[(c << 18) + (e << 9) + d] = (__bf16)wk[i];
}

// x fp32 [B,T,N,D] -> bf16 same layout
__global__ void k_castx(const float* __restrict__ x, __bf16* __restrict__ o) {
    size_t i = ((size_t)blockIdx.x * 256 + threadIdx.x) * 8;
    float4 f0 = *(const float4*)(x + i);
    float4 f1 = *(const float4*)(x + i + 4);
    bf16x8 v;
    v[0] = (__bf16)f0.x; v[1] = (__bf16)f0.y; v[2] = (__bf16)f0.z; v[3] = (__bf16)f0.w;
    v[4] = (__bf16)f1.x; v[5] = (__bf16)f1.y; v[6] = (__bf16)f1.z; v[7] = (__bf16)f1.w;
    *(bf16x8*)(o + i) = v;
}

// ---------------------------------------------------------------------------
// Fused QKV projection, 8-phase 256^2 schedule.
// Per n: one GEMM M=1536 x E=1536 (Wq || Wv || Wk[c]) x K=512.
// Grid: 36 tiles (6 m x 6 e) x 64 n, XCD-contiguous swizzle. 512 thr = 8 waves
// (2M x 4N), per-wave output 128x64, BK=64, 2x double-buffered LDS (128 KiB).
// Per K-tile: 4 phases x 16 MFMA; next tile's 8 global_load_lds issued in
// phases 0-1; single vmcnt(0) at tile end (loads >=2 phases old -> no drain).
__launch_bounds__(512, 2)
__global__ void k_qkv(const __bf16* __restrict__ xb,
                      const __bf16* __restrict__ WqE, const __bf16* __restrict__ WvE,
                      const __bf16* __restrict__ WkE,
                      const float* __restrict__ bq, const float* __restrict__ bv,
                      const float* __restrict__ bk, const int* __restrict__ cid,
                      __bf16* __restrict__ Qw, __bf16* __restrict__ Kw,
                      __bf16* __restrict__ Vw) {
    // XCD-contiguous bijective swizzle: 2304 blocks = 8 XCDs * 288.
    const int g   = blockIdx.y * 36 + blockIdx.x;
    const int s   = (g & 7) * 288 + (g >> 3);
    const int n   = s / 36;
    const int r36 = s - n * 36;
    const int mx  = r36 / 6;
    const int ey  = r36 - mx * 6;
    const int m0  = mx * 256;
    const int e0  = ey * 256;
    const int seg  = e0 >> 9;      // 0=Q 1=V 2=K
    const int eoff = e0 & 511;     // 0 or 256
    const int c    = cid[n];

    const __bf16* Wb = (seg == 0) ? WqE : (seg == 1) ? WvE : (WkE + ((size_t)c << 18));
    __bf16*       Ob = (seg == 0) ? Qw : (seg == 1) ? Vw : Kw;

    __shared__ __align__(16) __bf16 As[2][256 * 64];   // 64 KiB
    __shared__ __align__(16) __bf16 Bs[2][256 * 64];   // 64 KiB

    const int tid  = threadIdx.x;
    const int lane = tid & 63;
    const int w    = tid >> 6;         // 0..7
    const int wm2  = w >> 2;           // M half (0..1)
    const int wn4  = w & 3;            // N quarter (0..3)
    const int l15  = lane & 15, qd = lane >> 4;

    // staging: each instr covers 64 rows x 64 k; thread -> (row, 16B chunk)
    const int sr  = tid >> 3;          // 0..63
    const int sch = tid & 7;           // 0..7
    const int sw8 = (sch ^ (sr & 7)) * 8;
    const __bf16* aG = xb + ((size_t)(m0 + sr) * 64 + n) * 512 + sw8;
    const __bf16* bG = Wb + ((size_t)(eoff + sr) << 9) + sw8;
    const int ldst = tid * 8;          // LDS element offset within a 64-row slot

    // fragment read constants (read-side swizzle)
    const int co0  = (qd ^ (l15 & 7)) * 8;   // kc=0 chunk; kc=1 = co0 ^ 32
    const int arow = wm2 * 128 + l15;
    const int brow = wn4 * 64 + l15;

    f32x4 acc[8][4];
#pragma unroll
    for (int i = 0; i < 8; ++i)
#pragma unroll
        for (int j = 0; j < 4; ++j) acc[i][j] = (f32x4){0.f, 0.f, 0.f, 0.f};

    // prologue: stage K-tile 0 into buffer 0
#pragma unroll
    for (int q = 0; q < 4; ++q) {
        async16(aG + (size_t)q * 2097152, &As[0][q * 4096 + ldst]);
        async16(bG + (size_t)q * 32768,   &Bs[0][q * 4096 + ldst]);
    }
    asm volatile("s_waitcnt vmcnt(0)" ::: "memory");
    __builtin_amdgcn_s_barrier();

    bf16x8 bfr[4][2];
    for (int kt = 0; kt < 8; ++kt) {
        const int cb = kt & 1, nb = cb ^ 1;
        const int kn = (kt + 1) * 64;
#pragma unroll
        for (int q = 0; q < 4; ++q) {
            // issue next tile's staging early (phases 0-1: 2 slots A + 2 slots B each)
            if (q < 2 && kt < 7) {
#pragma unroll
                for (int h = 0; h < 2; ++h) {
                    const int sl = 2 * q + h;
                    async16(aG + (size_t)sl * 2097152 + kn, &As[nb][sl * 4096 + ldst]);
                    async16(bG + (size_t)sl * 32768 + kn,   &Bs[nb][sl * 4096 + ldst]);
                }
            }
            if (q == 0) {
#pragma unroll
                for (int j = 0; j < 4; ++j) {
                    bfr[j][0] = *(const bf16x8*)&Bs[cb][(brow + j * 16) * 64 + co0];
                    bfr[j][1] = *(const bf16x8*)&Bs[cb][(brow + j * 16) * 64 + (co0 ^ 32)];
                }
            }
            bf16x8 a00 = *(const bf16x8*)&As[cb][(arow + (2 * q) * 16) * 64 + co0];
            bf16x8 a01 = *(const bf16x8*)&As[cb][(arow + (2 * q) * 16) * 64 + (co0 ^ 32)];
            bf16x8 a10 = *(const bf16x8*)&As[cb][(arow + (2 * q + 1) * 16) * 64 + co0];
            bf16x8 a11 = *(const bf16x8*)&As[cb][(arow + (2 * q + 1) * 16) * 64 + (co0 ^ 32)];

            __builtin_amdgcn_s_barrier();
            asm volatile("s_waitcnt lgkmcnt(0)" ::: "memory");
            __builtin_amdgcn_sched_barrier(0);
            __builtin_amdgcn_s_setprio(1);
#pragma unroll
            for (int j = 0; j < 4; ++j) {
                acc[2 * q][j]     = MFMA16(a00, bfr[j][0], acc[2 * q][j]);
                acc[2 * q + 1][j] = MFMA16(a10, bfr[j][0], acc[2 * q + 1][j]);
            }
#pragma unroll
            for (int j = 0; j < 4; ++j) {
                acc[2 * q][j]     = MFMA16(a01, bfr[j][1], acc[2 * q][j]);
                acc[2 * q + 1][j] = MFMA16(a11, bfr[j][1], acc[2 * q + 1][j]);
            }
            __builtin_amdgcn_s_setprio(0);
            if (q == 3) asm volatile("s_waitcnt vmcnt(0)" ::: "memory");
            __builtin_amdgcn_s_barrier();
        }
    }

    float bias[4];
#pragma unroll
    for (int j = 0; j < 4; ++j) {
        int e = eoff + wn4 * 64 + j * 16 + l15;
        bias[j] = (seg == 0) ? bq[e] : (seg == 1) ? bv[e] : bk[(c << 9) + e];
    }
#pragma unroll
    for (int i = 0; i < 8; ++i) {
#pragma unroll
        for (int rx = 0; rx < 4; ++rx) {
            int m  = m0 + wm2 * 128 + i * 16 + qd * 4 + rx;
            int bb = m / 192;
            int tt = m - bb * 192;
            size_t ro = ((size_t)(bb * 64 + n) * 192 + tt) << 9;
#pragma unroll
            for (int j = 0; j < 4; ++j) {
                int e = eoff + wn4 * 64 + j * 16 + l15;
                Ob[ro + e] = (__bf16)(acc[i][j][rx] + bias[j]);
            }
        }
    }
}

// ---------------------------------------------------------------------------
// Attention, one (b,n,h) per block; 12 waves each own one 16-row Q strip.
__launch_bounds__(768)
__global__ void k_attn(const __bf16* __restrict__ Qw, const __bf16* __restrict__ Kw,
                       const __bf16* __restrict__ Vw, __bf16* __restrict__ Ow) {
    const int h = blockIdx.x, n = blockIdx.y, b = blockIdx.z;
    __shared__ __align__(16) __bf16 Ks[192 * 72];   // [s][k] 27.6 KB
    __shared__ __align__(16) __bf16 Vt[64 * 192];   // [e][s] chunk-swizzled 24.6 KB
    __shared__ __align__(16) __bf16 Ps[192 * 200];  // [t][s] 76.8 KB

    const int tid  = threadIdx.x;
    const int lane = tid & 63, w = tid >> 6;
    const int l15  = lane & 15, qd = lane >> 4;
    const size_t base = ((size_t)((b * 64 + n) * 192) << 9) + h * 64;

    for (int i = tid; i < 1536; i += 768) {  // K rows, b128
        int row = i >> 3, pp = i & 7;
        *(bf16x8*)&Ks[row * 72 + 8 * pp] =
            *(const bf16x8*)(Kw + base + ((size_t)row << 9) + 8 * pp);
    }
    // V^T: column gather (coalesced 128B reads) + one swizzled b128 write.
    // Vt[e][s-chunk c] stored at chunk position c ^ (e&7), row stride 192 elems.
#pragma unroll
    for (int rr = 0; rr < 2; ++rr) {
        int idx = rr * 768 + tid;          // 0..1535
        int e = idx & 63, sb = idx >> 6;   // sb 0..23
        bf16x8 v;
#pragma unroll
        for (int j = 0; j < 8; ++j)
            v[j] = Vw[base + (size_t)(sb * 8 + j) * 512 + e];
        *(bf16x8*)&Vt[e * 192 + ((sb ^ (e & 7)) * 8)] = v;
    }
    __syncthreads();

    const __bf16* qp = Qw + base + ((size_t)(16 * w + l15) << 9) + 8 * qd;
    bf16x8 aq0 = *(const bf16x8*)(qp);
    bf16x8 aq1 = *(const bf16x8*)(qp + 32);

    f32x4 S[12];
#pragma unroll
    for (int ct = 0; ct < 12; ++ct) {
        f32x4 acc = (f32x4){0.f, 0.f, 0.f, 0.f};
        bf16x8 b0 = *(const bf16x8*)&Ks[(16 * ct + l15) * 72 + 8 * qd];
        bf16x8 b1 = *(const bf16x8*)&Ks[(16 * ct + l15) * 72 + 32 + 8 * qd];
        acc = MFMA16(aq0, b0, acc);
        acc = MFMA16(aq1, b1, acc);
        S[ct] = acc;
    }

    float mx[4] = {-1e30f, -1e30f, -1e30f, -1e30f};
#pragma unroll
    for (int ct = 0; ct < 12; ++ct)
#pragma unroll
        for (int rx = 0; rx < 4; ++rx) mx[rx] = fmaxf(mx[rx], S[ct][rx]);
#pragma unroll
    for (int mk = 1; mk < 16; mk <<= 1)
#pragma unroll
        for (int rx = 0; rx < 4; ++rx) mx[rx] = fmaxf(mx[rx], __shfl_xor(mx[rx], mk, 64));

    const float sc = 0.125f * 1.44269504088896f;
    float sm[4] = {0.f, 0.f, 0.f, 0.f};
#pragma unroll
    for (int ct = 0; ct < 12; ++ct) {
#pragma unroll
        for (int rx = 0; rx < 4; ++rx) {
            float pe = exp2f((S[ct][rx] - mx[rx]) * sc);
            sm[rx] += pe;
            Ps[(w * 16 + qd * 4 + rx) * 200 + 16 * ct + l15] = (__bf16)pe;
        }
    }
#pragma unroll
    for (int mk = 1; mk < 16; mk <<= 1)
#pragma unroll
        for (int rx = 0; rx < 4; ++rx) sm[rx] += __shfl_xor(sm[rx], mk, 64);

    __syncthreads();

    float inv[4];
#pragma unroll
    for (int rx = 0; rx < 4; ++rx) inv[rx] = 1.f / sm[rx];

#pragma unroll
    for (int et = 0; et < 4; ++et) {
        f32x4 acc = (f32x4){0.f, 0.f, 0.f, 0.f};
#pragma unroll
        for (int sn = 0; sn < 6; ++sn) {
            bf16x8 pa = *(const bf16x8*)&Ps[(w * 16 + l15) * 200 + sn * 32 + 8 * qd];
            bf16x8 vb = *(const bf16x8*)
                &Vt[(et * 16 + l15) * 192 + (((sn * 4 + qd) ^ (l15 & 7)) * 8)];
            acc = MFMA16(pa, vb, acc);
        }
#pragma unroll
        for (int rx = 0; rx < 4; ++rx) {
            int t = 16 * w + 4 * qd + rx;
            Ow[base + ((size_t)t << 9) + et * 16 + l15] = (__bf16)(acc[rx] * inv[rx]);
        }
    }
}

// ---------------------------------------------------------------------------
// Output projection: 128x128 tile, BK=64, async staging, XOR swizzle.
__launch_bounds__(256)
__global__ void k_proj(const __bf16* __restrict__ Ow, const __bf16* __restrict__ WpE,
                       const float* __restrict__ bp, float* __restrict__ out) {
    const int n  = blockIdx.z;
    const int m0 = blockIdx.x * 128;
    const int e0 = blockIdx.y * 128;
    __shared__ __align__(16) __bf16 As[128 * 64];
    __shared__ __align__(16) __bf16 Bs[128 * 64];

    const int tid  = threadIdx.x;
    const int lane = tid & 63, w = tid >> 6;
    const int wm   = w >> 1, wn = w & 1;
    const int l15  = lane & 15, qd = lane >> 4;
    const int lr   = lane >> 3, lc = lane & 7;
    const int sc8  = (lc ^ lr) * 8;
    const int sw   = l15 & 7;

    const __bf16* agj[4];
#pragma unroll
    for (int j = 0; j < 4; ++j) {
        int m  = m0 + w * 32 + j * 8 + lr;
        int bb = m / 192;
        int tt = m - bb * 192;
        agj[j] = Ow + (((size_t)(bb * 64 + n) * 192 + tt) << 9) + sc8;
    }
    __bf16* al = As + w * 2048 + lr * 64 + lc * 8;
    const __bf16* bg  = WpE + ((size_t)(e0 + w * 32 + lr) << 9) + sc8;
    __bf16*       blp = Bs + w * 2048 + lr * 64 + lc * 8;

    f32x4 acc[4][4];
#pragma unroll
    for (int i = 0; i < 4; ++i)
#pragma unroll
        for (int j = 0; j < 4; ++j) acc[i][j] = (f32x4){0.f, 0.f, 0.f, 0.f};

    for (int kk = 0; kk < 8; ++kk) {
        const int k0 = kk * 64;
        __syncthreads();
#pragma unroll
        for (int j = 0; j < 4; ++j) {
            async16(agj[j] + k0, al + j * 512);
            async16(bg + j * 4096 + k0, blp + j * 512);
        }
        __syncthreads();

#pragma unroll
        for (int kc = 0; kc < 2; ++kc) {
            const int co = ((kc * 4 + qd) ^ sw) * 8;
            bf16x8 a0 = *(const bf16x8*)&As[(wm * 64 + l15) * 64 + co];
            bf16x8 a1 = *(const bf16x8*)&As[(wm * 64 + 16 + l15) * 64 + co];
            bf16x8 a2 = *(const bf16x8*)&As[(wm * 64 + 32 + l15) * 64 + co];
            bf16x8 a3 = *(const bf16x8*)&As[(wm * 64 + 48 + l15) * 64 + co];
#pragma unroll
            for (int j = 0; j < 4; ++j) {
                bf16x8 fb = *(const bf16x8*)&Bs[(wn * 64 + j * 16 + l15) * 64 + co];
                acc[0][j] = MFMA16(a0, fb, acc[0][j]);
                acc[1][j] = MFMA16(a1, fb, acc[1][j]);
                acc[2][j] = MFMA16(a2, fb, acc[2][j]);
                acc[3][j] = MFMA16(a3, fb, acc[3][j]);
            }
        }
    }

    float bias[4];
#pragma unroll
    for (int j = 0; j < 4; ++j) bias[j] = bp[e0 + wn * 64 + j * 16 + l15];
#pragma unroll
    for (int i = 0; i < 4; ++i) {
#pragma unroll
        for (int rx = 0; rx < 4; ++rx) {
            int m = m0 + wm * 64 + i * 16 + qd * 4 + rx;
            size_t ro = ((size_t)(m * 64 + n)) << 9;
#pragma unroll
            for (int j = 0; j < 4; ++j) {
                int e = e0 + wn * 64 + j * 16 + l15;
                out[ro + e] = acc[i][j][rx] + bias[j];
            }
        }
    }
}

// ---------------------------------------------------------------------------
extern "C" void kernel_launch(void* const* d_in, const int* in_sizes, int n_in,
                              void* d_out, int out_size, void* d_ws, size_t ws_size,
                              hipStream_t stream) {
    const float* x    = (const float*)d_in[0];
    const float* Wq_w = (const float*)d_in[1];
    const float* Wq_b = (const float*)d_in[2];
    const float* Wv_w = (const float*)d_in[3];
    const float* Wv_b = (const float*)d_in[4];
    const float* Wk   = (const float*)d_in[5];
    const float* bk   = (const float*)d_in[6];
    const float* Wp   = (const float*)d_in[7];
    const float* bp   = (const float*)d_in[8];
    const int*   cid  = (const int*)d_in[9];
    float* out = (float*)d_out;

    __bf16* WqE = (__bf16*)d_ws;
    __bf16* WvE = WqE + (1 << 18);
    __bf16* WpE = WvE + (1 << 18);
    __bf16* WkE = WpE + (1 << 18);
    __bf16* Qw  = WkE + (8 << 18);
    __bf16* Kw  = Qw + 50331648LL;
    __bf16* Vw  = Kw + 50331648LL;
    __bf16* XO  = Vw + 50331648LL;  // xbf during projections, Ow after attn

    k_cast3<<<1024, 256, 0, stream>>>(Wq_w, Wv_w, Wp, WqE, WvE, WpE);
    k_twk<<<8192, 256, 0, stream>>>(Wk, WkE);
    k_castx<<<24576, 256, 0, stream>>>(x, XO);
    k_qkv<<<dim3(36, 64), 512, 0, stream>>>(XO, WqE, WvE, WkE, Wq_b, Wv_b, bk, cid,
                                            Qw, Kw, Vw);
    k_attn<<<dim3(8, 64, 8), 768, 0, stream>>>(Qw, Kw, Vw, XO);
    k_proj<<<dim3(12, 4, 64), 256, 0, stream>>>(XO, WpE, bp, out);
}

// Round 2
// 802.237 us; speedup vs baseline: 1.0745x; 1.0745x over previous
//
#include <hip/hip_runtime.h>
#include <hip/hip_bf16.h>

typedef __bf16 bf16x8 __attribute__((ext_vector_type(8)));
typedef float  f32x4  __attribute__((ext_vector_type(4)));

#define MFMA16(a, b, c) __builtin_amdgcn_mfma_f32_16x16x32_bf16(a, b, c, 0, 0, 0)

// async global->LDS, 16 B per lane. LDS dest is wave-uniform base + lane*16;
// the GLOBAL address is per-lane free — we exploit that for the XOR swizzle.
__device__ __forceinline__ void async16(const __bf16* g, __bf16* l) {
    __builtin_amdgcn_global_load_lds(
        (const __attribute__((address_space(1))) unsigned int*)g,
        (__attribute__((address_space(3))) unsigned int*)l, 16, 0, 0);
}

// B=8 T=192 N=64 D=512 H=8 DH=64 C=8 ; per-n GEMM rows M = B*T = 1536

// ---------------------------------------------------------------------------
__global__ void k_cast3(const float* __restrict__ wq, const float* __restrict__ wv,
                        const float* __restrict__ wp,
                        __bf16* __restrict__ oq, __bf16* __restrict__ ov,
                        __bf16* __restrict__ op) {
    int i = blockIdx.x * 256 + threadIdx.x;
    oq[i] = (__bf16)wq[i];
    ov[i] = (__bf16)wv[i];
    op[i] = (__bf16)wp[i];
}

// Wk [c][d][e] fp32 -> bf16 [c][e][d]
__global__ void k_twk(const float* __restrict__ wk, __bf16* __restrict__ o) {
    int i = blockIdx.x * 256 + threadIdx.x;
    int c = i >> 18;
    int r = i & 262143;
    int d = r >> 9;
    int e = r & 511;
    o[(c << 18) + (e << 9) + d] = (__bf16)wk[i];
}

// x fp32 [B,T,N,D] -> bf16 same layout
__global__ void k_castx(const float* __restrict__ x, __bf16* __restrict__ o) {
    size_t i = ((size_t)blockIdx.x * 256 + threadIdx.x) * 8;
    float4 f0 = *(const float4*)(x + i);
    float4 f1 = *(const float4*)(x + i + 4);
    bf16x8 v;
    v[0] = (__bf16)f0.x; v[1] = (__bf16)f0.y; v[2] = (__bf16)f0.z; v[3] = (__bf16)f0.w;
    v[4] = (__bf16)f1.x; v[5] = (__bf16)f1.y; v[6] = (__bf16)f1.z; v[7] = (__bf16)f1.w;
    *(bf16x8*)(o + i) = v;
}

// ---------------------------------------------------------------------------
// Fused QKV projection, 4-deep ring pipeline with COUNTED vmcnt (T3+T4+T5).
// Per n: one GEMM M=1536 x E=1536 (Wq || Wv || Wk[c]) x K=512.
// Grid: 36 tiles (6m x 6e) x 64 n, XCD-contiguous swizzle. 512 thr = 8 waves
// (2M x 4N), per-wave output 128x64. BK=32, 16 K-steps.
// Ring of 4 LDS slots (A 256x32 + B 256x32 = 32 KiB each, 128 KiB total).
// Step t issues slot t+3 (4 global_load_lds) -> 12 loads / 3 slots always in
// flight; end-of-step wait is vmcnt(8) = oldest slot only. Never drains to 0
// in the main loop (first vmcnt(0) is at step 14 of 16).
// LDS chunk swizzle: 4 16B-chunks per 32-k row; chunk c stored at c^(row&3),
// read back with the same XOR -> a wave's 64-lane b128 read is a permutation
// of a contiguous 1 KiB region = zero bank conflicts.
__launch_bounds__(512, 2)
__global__ void k_qkv(const __bf16* __restrict__ xb,
                      const __bf16* __restrict__ WqE, const __bf16* __restrict__ WvE,
                      const __bf16* __restrict__ WkE,
                      const float* __restrict__ bq, const float* __restrict__ bv,
                      const float* __restrict__ bk, const int* __restrict__ cid,
                      __bf16* __restrict__ Qw, __bf16* __restrict__ Kw,
                      __bf16* __restrict__ Vw) {
    // XCD-contiguous bijective swizzle: 2304 blocks = 8 XCDs * 288.
    const int g   = blockIdx.y * 36 + blockIdx.x;
    const int s   = (g & 7) * 288 + (g >> 3);
    const int n   = s / 36;
    const int r36 = s - n * 36;
    const int mx  = r36 / 6;
    const int ey  = r36 - mx * 6;
    const int m0  = mx * 256;
    const int e0  = ey * 256;
    const int seg  = e0 >> 9;      // 0=Q 1=V 2=K
    const int eoff = e0 & 511;     // 0 or 256
    const int c    = cid[n];

    const __bf16* Wb = (seg == 0) ? WqE : (seg == 1) ? WvE : (WkE + ((size_t)c << 18));
    __bf16*       Ob = (seg == 0) ? Qw : (seg == 1) ? Vw : Kw;

    __shared__ __align__(16) __bf16 Ar[4][256 * 32];   // 64 KiB ring
    __shared__ __align__(16) __bf16 Br[4][256 * 32];   // 64 KiB ring

    const int tid  = threadIdx.x;
    const int lane = tid & 63;
    const int w    = tid >> 6;         // 0..7
    const int wm2  = w >> 2;           // M half (0..1)
    const int wn4  = w & 3;            // N quarter (0..3)
    const int l15  = lane & 15, qd = lane >> 4;

    // staging: thread -> (row = tid>>2 of 128, LDS chunk pos = tid&3)
    const int sr  = tid >> 2;
    const int sp  = tid & 3;
    const int sch = (sp ^ (sr & 3)) * 8;    // pre-swizzled global chunk
    const __bf16* aG0 = xb + ((size_t)(m0 + sr) * 64 + n) * 512 + sch;
    const __bf16* aG1 = aG0 + (size_t)128 * 64 * 512;
    const __bf16* bG0 = Wb + ((size_t)(eoff + sr) << 9) + sch;
    const __bf16* bG1 = bG0 + ((size_t)128 << 9);

    // fragment read constants (read-side swizzle, same XOR)
    const int cro   = (qd ^ (l15 & 3)) * 8;
    const int arow0 = (wm2 * 128 + l15) * 32;
    const int brow0 = (wn4 * 64 + l15) * 32;

    f32x4 acc[8][4];
#pragma unroll
    for (int i = 0; i < 8; ++i)
#pragma unroll
        for (int j = 0; j < 4; ++j) acc[i][j] = (f32x4){0.f, 0.f, 0.f, 0.f};

    auto issue = [&](int t) {
        const int slot = t & 3;
        const int k0 = t * 32;
        __bf16* ad = &Ar[slot][tid * 8];
        __bf16* bd = &Br[slot][tid * 8];
        async16(aG0 + k0, ad);
        async16(aG1 + k0, ad + 4096);
        async16(bG0 + k0, bd);
        async16(bG1 + k0, bd + 4096);
    };
    auto compute = [&](int slot) {
        const __bf16* Asl = Ar[slot];
        const __bf16* Bsl = Br[slot];
        bf16x8 bfr[4], af[8];
#pragma unroll
        for (int j = 0; j < 4; ++j)
            bfr[j] = *(const bf16x8*)&Bsl[brow0 + j * 512 + cro];
#pragma unroll
        for (int i = 0; i < 8; ++i)
            af[i] = *(const bf16x8*)&Asl[arow0 + i * 512 + cro];
        asm volatile("s_waitcnt lgkmcnt(0)" ::: "memory");
        __builtin_amdgcn_sched_barrier(0);
        __builtin_amdgcn_s_setprio(1);
#pragma unroll
        for (int i = 0; i < 8; ++i)
#pragma unroll
            for (int j = 0; j < 4; ++j)
                acc[i][j] = MFMA16(af[i], bfr[j], acc[i][j]);
        __builtin_amdgcn_s_setprio(0);
    };

    // prologue: fill slots 0,1,2 (12 loads); wait the oldest slot only.
    issue(0); issue(1); issue(2);
    asm volatile("s_waitcnt vmcnt(8)" ::: "memory");
    __builtin_amdgcn_s_barrier();
    __builtin_amdgcn_sched_barrier(0);

    // steady state: 12 loads in flight, wait vmcnt(8) (= slot t+1 ready).
    for (int t = 0; t < 13; ++t) {
        issue(t + 3);
        compute(t & 3);
        asm volatile("s_waitcnt vmcnt(8)" ::: "memory");
        __builtin_amdgcn_s_barrier();
        __builtin_amdgcn_sched_barrier(0);
    }
    // epilogue: drain 8 -> 4 -> 0 outstanding.
    compute(1);   // t=13
    asm volatile("s_waitcnt vmcnt(4)" ::: "memory");
    __builtin_amdgcn_s_barrier();
    __builtin_amdgcn_sched_barrier(0);
    compute(2);   // t=14
    asm volatile("s_waitcnt vmcnt(0)" ::: "memory");
    __builtin_amdgcn_s_barrier();
    __builtin_amdgcn_sched_barrier(0);
    compute(3);   // t=15

    float bias[4];
#pragma unroll
    for (int j = 0; j < 4; ++j) {
        int e = eoff + wn4 * 64 + j * 16 + l15;
        bias[j] = (seg == 0) ? bq[e] : (seg == 1) ? bv[e] : bk[(c << 9) + e];
    }
#pragma unroll
    for (int i = 0; i < 8; ++i) {
#pragma unroll
        for (int rx = 0; rx < 4; ++rx) {
            int m  = m0 + wm2 * 128 + i * 16 + qd * 4 + rx;
            int bb = m / 192;
            int tt = m - bb * 192;
            size_t ro = ((size_t)(bb * 64 + n) * 192 + tt) << 9;
#pragma unroll
            for (int j = 0; j < 4; ++j) {
                int e = eoff + wn4 * 64 + j * 16 + l15;
                Ob[ro + e] = (__bf16)(acc[i][j][rx] + bias[j]);
            }
        }
    }
}

// ---------------------------------------------------------------------------
// Attention, one (b,n,h) per block; 12 waves each own one 16-row Q strip.
__launch_bounds__(768)
__global__ void k_attn(const __bf16* __restrict__ Qw, const __bf16* __restrict__ Kw,
                       const __bf16* __restrict__ Vw, __bf16* __restrict__ Ow) {
    const int h = blockIdx.x, n = blockIdx.y, b = blockIdx.z;
    __shared__ __align__(16) __bf16 Ks[192 * 72];   // [s][k] 27.6 KB
    __shared__ __align__(16) __bf16 Vt[64 * 192];   // [e][s] chunk-swizzled 24.6 KB
    __shared__ __align__(16) __bf16 Ps[192 * 200];  // [t][s] 76.8 KB

    const int tid  = threadIdx.x;
    const int lane = tid & 63, w = tid >> 6;
    const int l15  = lane & 15, qd = lane >> 4;
    const size_t base = ((size_t)((b * 64 + n) * 192) << 9) + h * 64;

    for (int i = tid; i < 1536; i += 768) {  // K rows, b128
        int row = i >> 3, pp = i & 7;
        *(bf16x8*)&Ks[row * 72 + 8 * pp] =
            *(const bf16x8*)(Kw + base + ((size_t)row << 9) + 8 * pp);
    }
    // V^T: column gather (coalesced 128B reads) + one swizzled b128 write.
    // Vt[e][s-chunk c] stored at chunk position c ^ (e&7), row stride 192 elems.
#pragma unroll
    for (int rr = 0; rr < 2; ++rr) {
        int idx = rr * 768 + tid;          // 0..1535
        int e = idx & 63, sb = idx >> 6;   // sb 0..23
        bf16x8 v;
#pragma unroll
        for (int j = 0; j < 8; ++j)
            v[j] = Vw[base + (size_t)(sb * 8 + j) * 512 + e];
        *(bf16x8*)&Vt[e * 192 + ((sb ^ (e & 7)) * 8)] = v;
    }
    __syncthreads();

    const __bf16* qp = Qw + base + ((size_t)(16 * w + l15) << 9) + 8 * qd;
    bf16x8 aq0 = *(const bf16x8*)(qp);
    bf16x8 aq1 = *(const bf16x8*)(qp + 32);

    f32x4 S[12];
#pragma unroll
    for (int ct = 0; ct < 12; ++ct) {
        f32x4 acc = (f32x4){0.f, 0.f, 0.f, 0.f};
        bf16x8 b0 = *(const bf16x8*)&Ks[(16 * ct + l15) * 72 + 8 * qd];
        bf16x8 b1 = *(const bf16x8*)&Ks[(16 * ct + l15) * 72 + 32 + 8 * qd];
        acc = MFMA16(aq0, b0, acc);
        acc = MFMA16(aq1, b1, acc);
        S[ct] = acc;
    }

    float mx[4] = {-1e30f, -1e30f, -1e30f, -1e30f};
#pragma unroll
    for (int ct = 0; ct < 12; ++ct)
#pragma unroll
        for (int rx = 0; rx < 4; ++rx) mx[rx] = fmaxf(mx[rx], S[ct][rx]);
#pragma unroll
    for (int mk = 1; mk < 16; mk <<= 1)
#pragma unroll
        for (int rx = 0; rx < 4; ++rx) mx[rx] = fmaxf(mx[rx], __shfl_xor(mx[rx], mk, 64));

    const float sc = 0.125f * 1.44269504088896f;
    float sm[4] = {0.f, 0.f, 0.f, 0.f};
#pragma unroll
    for (int ct = 0; ct < 12; ++ct) {
#pragma unroll
        for (int rx = 0; rx < 4; ++rx) {
            float pe = exp2f((S[ct][rx] - mx[rx]) * sc);
            sm[rx] += pe;
            Ps[(w * 16 + qd * 4 + rx) * 200 + 16 * ct + l15] = (__bf16)pe;
        }
    }
#pragma unroll
    for (int mk = 1; mk < 16; mk <<= 1)
#pragma unroll
        for (int rx = 0; rx < 4; ++rx) sm[rx] += __shfl_xor(sm[rx], mk, 64);

    __syncthreads();

    float inv[4];
#pragma unroll
    for (int rx = 0; rx < 4; ++rx) inv[rx] = 1.f / sm[rx];

#pragma unroll
    for (int et = 0; et < 4; ++et) {
        f32x4 acc = (f32x4){0.f, 0.f, 0.f, 0.f};
#pragma unroll
        for (int sn = 0; sn < 6; ++sn) {
            bf16x8 pa = *(const bf16x8*)&Ps[(w * 16 + l15) * 200 + sn * 32 + 8 * qd];
            bf16x8 vb = *(const bf16x8*)
                &Vt[(et * 16 + l15) * 192 + (((sn * 4 + qd) ^ (l15 & 7)) * 8)];
            acc = MFMA16(pa, vb, acc);
        }
#pragma unroll
        for (int rx = 0; rx < 4; ++rx) {
            int t = 16 * w + 4 * qd + rx;
            Ow[base + ((size_t)t << 9) + et * 16 + l15] = (__bf16)(acc[rx] * inv[rx]);
        }
    }
}

// ---------------------------------------------------------------------------
// Output projection: 128x128 tile, BK=64, async staging, XOR swizzle.
__launch_bounds__(256)
__global__ void k_proj(const __bf16* __restrict__ Ow, const __bf16* __restrict__ WpE,
                       const float* __restrict__ bp, float* __restrict__ out) {
    const int n  = blockIdx.z;
    const int m0 = blockIdx.x * 128;
    const int e0 = blockIdx.y * 128;
    __shared__ __align__(16) __bf16 As[128 * 64];
    __shared__ __align__(16) __bf16 Bs[128 * 64];

    const int tid  = threadIdx.x;
    const int lane = tid & 63, w = tid >> 6;
    const int wm   = w >> 1, wn = w & 1;
    const int l15  = lane & 15, qd = lane >> 4;
    const int lr   = lane >> 3, lc = lane & 7;
    const int sc8  = (lc ^ lr) * 8;
    const int sw   = l15 & 7;

    const __bf16* agj[4];
#pragma unroll
    for (int j = 0; j < 4; ++j) {
        int m  = m0 + w * 32 + j * 8 + lr;
        int bb = m / 192;
        int tt = m - bb * 192;
        agj[j] = Ow + (((size_t)(bb * 64 + n) * 192 + tt) << 9) + sc8;
    }
    __bf16* al = As + w * 2048 + lr * 64 + lc * 8;
    const __bf16* bg  = WpE + ((size_t)(e0 + w * 32 + lr) << 9) + sc8;
    __bf16*       blp = Bs + w * 2048 + lr * 64 + lc * 8;

    f32x4 acc[4][4];
#pragma unroll
    for (int i = 0; i < 4; ++i)
#pragma unroll
        for (int j = 0; j < 4; ++j) acc[i][j] = (f32x4){0.f, 0.f, 0.f, 0.f};

    for (int kk = 0; kk < 8; ++kk) {
        const int k0 = kk * 64;
        __syncthreads();
#pragma unroll
        for (int j = 0; j < 4; ++j) {
            async16(agj[j] + k0, al + j * 512);
            async16(bg + j * 4096 + k0, blp + j * 512);
        }
        __syncthreads();

#pragma unroll
        for (int kc = 0; kc < 2; ++kc) {
            const int co = ((kc * 4 + qd) ^ sw) * 8;
            bf16x8 a0 = *(const bf16x8*)&As[(wm * 64 + l15) * 64 + co];
            bf16x8 a1 = *(const bf16x8*)&As[(wm * 64 + 16 + l15) * 64 + co];
            bf16x8 a2 = *(const bf16x8*)&As[(wm * 64 + 32 + l15) * 64 + co];
            bf16x8 a3 = *(const bf16x8*)&As[(wm * 64 + 48 + l15) * 64 + co];
#pragma unroll
            for (int j = 0; j < 4; ++j) {
                bf16x8 fb = *(const bf16x8*)&Bs[(wn * 64 + j * 16 + l15) * 64 + co];
                acc[0][j] = MFMA16(a0, fb, acc[0][j]);
                acc[1][j] = MFMA16(a1, fb, acc[1][j]);
                acc[2][j] = MFMA16(a2, fb, acc[2][j]);
                acc[3][j] = MFMA16(a3, fb, acc[3][j]);
            }
        }
    }

    float bias[4];
#pragma unroll
    for (int j = 0; j < 4; ++j) bias[j] = bp[e0 + wn * 64 + j * 16 + l15];
#pragma unroll
    for (int i = 0; i < 4; ++i) {
#pragma unroll
        for (int rx = 0; rx < 4; ++rx) {
            int m = m0 + wm * 64 + i * 16 + qd * 4 + rx;
            size_t ro = ((size_t)(m * 64 + n)) << 9;
#pragma unroll
            for (int j = 0; j < 4; ++j) {
                int e = e0 + wn * 64 + j * 16 + l15;
                out[ro + e] = acc[i][j][rx] + bias[j];
            }
        }
    }
}

// ---------------------------------------------------------------------------
extern "C" void kernel_launch(void* const* d_in, const int* in_sizes, int n_in,
                              void* d_out, int out_size, void* d_ws, size_t ws_size,
                              hipStream_t stream) {
    const float* x    = (const float*)d_in[0];
    const float* Wq_w = (const float*)d_in[1];
    const float* Wq_b = (const float*)d_in[2];
    const float* Wv_w = (const float*)d_in[3];
    const float* Wv_b = (const float*)d_in[4];
    const float* Wk   = (const float*)d_in[5];
    const float* bk   = (const float*)d_in[6];
    const float* Wp   = (const float*)d_in[7];
    const float* bp   = (const float*)d_in[8];
    const int*   cid  = (const int*)d_in[9];
    float* out = (float*)d_out;

    __bf16* WqE = (__bf16*)d_ws;
    __bf16* WvE = WqE + (1 << 18);
    __bf16* WpE = WvE + (1 << 18);
    __bf16* WkE = WpE + (1 << 18);
    __bf16* Qw  = WkE + (8 << 18);
    __bf16* Kw  = Qw + 50331648LL;
    __bf16* Vw  = Kw + 50331648LL;
    __bf16* XO  = Vw + 50331648LL;  // xbf during projections, Ow after attn

    k_cast3<<<1024, 256, 0, stream>>>(Wq_w, Wv_w, Wp, WqE, WvE, WpE);
    k_twk<<<8192, 256, 0, stream>>>(Wk, WkE);
    k_castx<<<24576, 256, 0, stream>>>(x, XO);
    k_qkv<<<dim3(36, 64), 512, 0, stream>>>(XO, WqE, WvE, WkE, Wq_b, Wv_b, bk, cid,
                                            Qw, Kw, Vw);
    k_attn<<<dim3(8, 64, 8), 768, 0, stream>>>(Qw, Kw, Vw, XO);
    k_proj<<<dim3(12, 4, 64), 256, 0, stream>>>(XO, WpE, bp, out);
}

// Round 3
// 783.550 us; speedup vs baseline: 1.1002x; 1.0238x over previous
//
#include <hip/hip_runtime.h>
#include <hip/hip_bf16.h>

typedef __bf16 bf16x8 __attribute__((ext_vector_type(8)));
typedef float  f32x4  __attribute__((ext_vector_type(4)));

#define MFMA16(a, b, c) __builtin_amdgcn_mfma_f32_16x16x32_bf16(a, b, c, 0, 0, 0)

// async global->LDS, 16 B per lane. LDS dest is wave-uniform base + lane*16;
// the GLOBAL address is per-lane free — we exploit that for the XOR swizzle.
__device__ __forceinline__ void async16(const __bf16* g, __bf16* l) {
    __builtin_amdgcn_global_load_lds(
        (const __attribute__((address_space(1))) unsigned int*)g,
        (__attribute__((address_space(3))) unsigned int*)l, 16, 0, 0);
}

// B=8 T=192 N=64 D=512 H=8 DH=64 C=8 ; per-n GEMM rows M = B*T = 1536
//
// BK=32 LDS tiles: row stride 64 B = HALF the 32-bank span, so row bit 0 is an
// in-bank-space address bit. Swizzle key must therefore be (row>>1)&3, NOT
// row&3 (round-2 bug: key low bit == row parity bit -> 4-way conflict).
// slot p of row r holds global chunk p ^ ((r>>1)&3); reader of global chunk qd
// reads slot qd ^ ((r>>1)&3). Bank group = (l15&1)*4 + (qd^((l15>>1)&3)):
// each of 8 slots hit exactly 2x per 16 lanes = 2-way = free.

// ---------------------------------------------------------------------------
__global__ void k_cast3(const float* __restrict__ wq, const float* __restrict__ wv,
                        const float* __restrict__ wp,
                        __bf16* __restrict__ oq, __bf16* __restrict__ ov,
                        __bf16* __restrict__ op) {
    int i = blockIdx.x * 256 + threadIdx.x;
    oq[i] = (__bf16)wq[i];
    ov[i] = (__bf16)wv[i];
    op[i] = (__bf16)wp[i];
}

// Wk [c][d][e] fp32 -> bf16 [c][e][d]
__global__ void k_twk(const float* __restrict__ wk, __bf16* __restrict__ o) {
    int i = blockIdx.x * 256 + threadIdx.x;
    int c = i >> 18;
    int r = i & 262143;
    int d = r >> 9;
    int e = r & 511;
    o[(c << 18) + (e << 9) + d] = (__bf16)wk[i];
}

// x fp32 [B,T,N,D] -> bf16 same layout
__global__ void k_castx(const float* __restrict__ x, __bf16* __restrict__ o) {
    size_t i = ((size_t)blockIdx.x * 256 + threadIdx.x) * 8;
    float4 f0 = *(const float4*)(x + i);
    float4 f1 = *(const float4*)(x + i + 4);
    bf16x8 v;
    v[0] = (__bf16)f0.x; v[1] = (__bf16)f0.y; v[2] = (__bf16)f0.z; v[3] = (__bf16)f0.w;
    v[4] = (__bf16)f1.x; v[5] = (__bf16)f1.y; v[6] = (__bf16)f1.z; v[7] = (__bf16)f1.w;
    *(bf16x8*)(o + i) = v;
}

// ---------------------------------------------------------------------------
// Fused QKV projection, 4-deep ring pipeline with COUNTED vmcnt (T3+T4+T5).
// Per n: one GEMM M=1536 x E=1536 (Wq || Wv || Wk[c]) x K=512.
// Grid: 36 tiles (6m x 6e) x 64 n, XCD-contiguous swizzle. 512 thr = 8 waves
// (2M x 4N), per-wave output 128x64. BK=32, 16 K-steps.
// Ring of 4 LDS slots; step t issues slot t+3 -> 12 loads / 3 slots always in
// flight; end-of-step wait is vmcnt(8) = oldest slot only. ds_read->MFMA
// scheduling is left to the compiler (fine-grained lgkmcnt interleave).
__launch_bounds__(512, 2)
__global__ void k_qkv(const __bf16* __restrict__ xb,
                      const __bf16* __restrict__ WqE, const __bf16* __restrict__ WvE,
                      const __bf16* __restrict__ WkE,
                      const float* __restrict__ bq, const float* __restrict__ bv,
                      const float* __restrict__ bk, const int* __restrict__ cid,
                      __bf16* __restrict__ Qw, __bf16* __restrict__ Kw,
                      __bf16* __restrict__ Vw) {
    // XCD-contiguous bijective swizzle: 2304 blocks = 8 XCDs * 288.
    const int g   = blockIdx.y * 36 + blockIdx.x;
    const int s   = (g & 7) * 288 + (g >> 3);
    const int n   = s / 36;
    const int r36 = s - n * 36;
    const int mx  = r36 / 6;
    const int ey  = r36 - mx * 6;
    const int m0  = mx * 256;
    const int e0  = ey * 256;
    const int seg  = e0 >> 9;      // 0=Q 1=V 2=K
    const int eoff = e0 & 511;     // 0 or 256
    const int c    = cid[n];

    const __bf16* Wb = (seg == 0) ? WqE : (seg == 1) ? WvE : (WkE + ((size_t)c << 18));
    __bf16*       Ob = (seg == 0) ? Qw : (seg == 1) ? Vw : Kw;

    __shared__ __align__(16) __bf16 Ar[4][256 * 32];   // 64 KiB ring
    __shared__ __align__(16) __bf16 Br[4][256 * 32];   // 64 KiB ring

    const int tid  = threadIdx.x;
    const int lane = tid & 63;
    const int w    = tid >> 6;         // 0..7
    const int wm2  = w >> 2;           // M half (0..1)
    const int wn4  = w & 3;            // N quarter (0..3)
    const int l15  = lane & 15, qd = lane >> 4;

    // staging: thread -> (row = tid>>2 of 128, LDS chunk pos = tid&3)
    const int sr  = tid >> 2;
    const int sp  = tid & 3;
    const int sch = (sp ^ ((sr >> 1) & 3)) * 8;   // pre-swizzled global chunk
    const __bf16* aG0 = xb + ((size_t)(m0 + sr) * 64 + n) * 512 + sch;
    const __bf16* aG1 = aG0 + (size_t)128 * 64 * 512;
    const __bf16* bG0 = Wb + ((size_t)(eoff + sr) << 9) + sch;
    const __bf16* bG1 = bG0 + ((size_t)128 << 9);

    // fragment read constants (read-side swizzle, same key; rows step by 16 so
    // (row>>1)&3 is invariant across the i/j sub-tiles)
    const int cro   = (qd ^ ((l15 >> 1) & 3)) * 8;
    const int arow0 = (wm2 * 128 + l15) * 32;
    const int brow0 = (wn4 * 64 + l15) * 32;

    f32x4 acc[8][4];
#pragma unroll
    for (int i = 0; i < 8; ++i)
#pragma unroll
        for (int j = 0; j < 4; ++j) acc[i][j] = (f32x4){0.f, 0.f, 0.f, 0.f};

    auto issue = [&](int t) {
        const int slot = t & 3;
        const int k0 = t * 32;
        __bf16* ad = &Ar[slot][tid * 8];
        __bf16* bd = &Br[slot][tid * 8];
        async16(aG0 + k0, ad);
        async16(aG1 + k0, ad + 4096);
        async16(bG0 + k0, bd);
        async16(bG1 + k0, bd + 4096);
    };
    auto compute = [&](int slot) {
        const __bf16* Asl = Ar[slot];
        const __bf16* Bsl = Br[slot];
        bf16x8 bfr[4], af[8];
#pragma unroll
        for (int j = 0; j < 4; ++j)
            bfr[j] = *(const bf16x8*)&Bsl[brow0 + j * 512 + cro];
#pragma unroll
        for (int i = 0; i < 8; ++i)
            af[i] = *(const bf16x8*)&Asl[arow0 + i * 512 + cro];
        __builtin_amdgcn_s_setprio(1);
#pragma unroll
        for (int i = 0; i < 8; ++i)
#pragma unroll
            for (int j = 0; j < 4; ++j)
                acc[i][j] = MFMA16(af[i], bfr[j], acc[i][j]);
        __builtin_amdgcn_s_setprio(0);
    };

    // prologue: fill slots 0,1,2 (12 loads); wait the oldest slot only.
    issue(0); issue(1); issue(2);
    asm volatile("s_waitcnt vmcnt(8)" ::: "memory");
    __builtin_amdgcn_s_barrier();

    // steady state: 12 loads in flight, wait vmcnt(8) (= slot t+1 ready).
    for (int t = 0; t < 13; ++t) {
        issue(t + 3);
        compute(t & 3);
        asm volatile("s_waitcnt vmcnt(8)" ::: "memory");
        __builtin_amdgcn_s_barrier();
    }
    // epilogue: drain 8 -> 4 -> 0 outstanding.
    compute(1);   // t=13
    asm volatile("s_waitcnt vmcnt(4)" ::: "memory");
    __builtin_amdgcn_s_barrier();
    compute(2);   // t=14
    asm volatile("s_waitcnt vmcnt(0)" ::: "memory");
    __builtin_amdgcn_s_barrier();
    compute(3);   // t=15

    float bias[4];
#pragma unroll
    for (int j = 0; j < 4; ++j) {
        int e = eoff + wn4 * 64 + j * 16 + l15;
        bias[j] = (seg == 0) ? bq[e] : (seg == 1) ? bv[e] : bk[(c << 9) + e];
    }
#pragma unroll
    for (int i = 0; i < 8; ++i) {
#pragma unroll
        for (int rx = 0; rx < 4; ++rx) {
            int m  = m0 + wm2 * 128 + i * 16 + qd * 4 + rx;
            int bb = m / 192;
            int tt = m - bb * 192;
            size_t ro = ((size_t)(bb * 64 + n) * 192 + tt) << 9;
#pragma unroll
            for (int j = 0; j < 4; ++j) {
                int e = eoff + wn4 * 64 + j * 16 + l15;
                Ob[ro + e] = (__bf16)(acc[i][j][rx] + bias[j]);
            }
        }
    }
}

// ---------------------------------------------------------------------------
// Attention, one (b,n,h) per block; 12 waves each own one 16-row Q strip.
__launch_bounds__(768)
__global__ void k_attn(const __bf16* __restrict__ Qw, const __bf16* __restrict__ Kw,
                       const __bf16* __restrict__ Vw, __bf16* __restrict__ Ow) {
    const int h = blockIdx.x, n = blockIdx.y, b = blockIdx.z;
    __shared__ __align__(16) __bf16 Ks[192 * 72];   // [s][k] 27.6 KB
    __shared__ __align__(16) __bf16 Vt[64 * 192];   // [e][s] chunk-swizzled 24.6 KB
    __shared__ __align__(16) __bf16 Ps[192 * 200];  // [t][s] 76.8 KB

    const int tid  = threadIdx.x;
    const int lane = tid & 63, w = tid >> 6;
    const int l15  = lane & 15, qd = lane >> 4;
    const size_t base = ((size_t)((b * 64 + n) * 192) << 9) + h * 64;

    for (int i = tid; i < 1536; i += 768) {  // K rows, b128
        int row = i >> 3, pp = i & 7;
        *(bf16x8*)&Ks[row * 72 + 8 * pp] =
            *(const bf16x8*)(Kw + base + ((size_t)row << 9) + 8 * pp);
    }
    // V^T: column gather (coalesced 128B reads) + one swizzled b128 write.
    // Vt[e][s-chunk c] stored at chunk position c ^ (e&7), row stride 192 elems.
#pragma unroll
    for (int rr = 0; rr < 2; ++rr) {
        int idx = rr * 768 + tid;          // 0..1535
        int e = idx & 63, sb = idx >> 6;   // sb 0..23
        bf16x8 v;
#pragma unroll
        for (int j = 0; j < 8; ++j)
            v[j] = Vw[base + (size_t)(sb * 8 + j) * 512 + e];
        *(bf16x8*)&Vt[e * 192 + ((sb ^ (e & 7)) * 8)] = v;
    }
    __syncthreads();

    const __bf16* qp = Qw + base + ((size_t)(16 * w + l15) << 9) + 8 * qd;
    bf16x8 aq0 = *(const bf16x8*)(qp);
    bf16x8 aq1 = *(const bf16x8*)(qp + 32);

    f32x4 S[12];
#pragma unroll
    for (int ct = 0; ct < 12; ++ct) {
        f32x4 acc = (f32x4){0.f, 0.f, 0.f, 0.f};
        bf16x8 b0 = *(const bf16x8*)&Ks[(16 * ct + l15) * 72 + 8 * qd];
        bf16x8 b1 = *(const bf16x8*)&Ks[(16 * ct + l15) * 72 + 32 + 8 * qd];
        acc = MFMA16(aq0, b0, acc);
        acc = MFMA16(aq1, b1, acc);
        S[ct] = acc;
    }

    float mx[4] = {-1e30f, -1e30f, -1e30f, -1e30f};
#pragma unroll
    for (int ct = 0; ct < 12; ++ct)
#pragma unroll
        for (int rx = 0; rx < 4; ++rx) mx[rx] = fmaxf(mx[rx], S[ct][rx]);
#pragma unroll
    for (int mk = 1; mk < 16; mk <<= 1)
#pragma unroll
        for (int rx = 0; rx < 4; ++rx) mx[rx] = fmaxf(mx[rx], __shfl_xor(mx[rx], mk, 64));

    const float sc = 0.125f * 1.44269504088896f;
    float sm[4] = {0.f, 0.f, 0.f, 0.f};
#pragma unroll
    for (int ct = 0; ct < 12; ++ct) {
#pragma unroll
        for (int rx = 0; rx < 4; ++rx) {
            float pe = exp2f((S[ct][rx] - mx[rx]) * sc);
            sm[rx] += pe;
            Ps[(w * 16 + qd * 4 + rx) * 200 + 16 * ct + l15] = (__bf16)pe;
        }
    }
#pragma unroll
    for (int mk = 1; mk < 16; mk <<= 1)
#pragma unroll
        for (int rx = 0; rx < 4; ++rx) sm[rx] += __shfl_xor(sm[rx], mk, 64);

    __syncthreads();

    float inv[4];
#pragma unroll
    for (int rx = 0; rx < 4; ++rx) inv[rx] = 1.f / sm[rx];

#pragma unroll
    for (int et = 0; et < 4; ++et) {
        f32x4 acc = (f32x4){0.f, 0.f, 0.f, 0.f};
#pragma unroll
        for (int sn = 0; sn < 6; ++sn) {
            bf16x8 pa = *(const bf16x8*)&Ps[(w * 16 + l15) * 200 + sn * 32 + 8 * qd];
            bf16x8 vb = *(const bf16x8*)
                &Vt[(et * 16 + l15) * 192 + (((sn * 4 + qd) ^ (l15 & 7)) * 8)];
            acc = MFMA16(pa, vb, acc);
        }
#pragma unroll
        for (int rx = 0; rx < 4; ++rx) {
            int t = 16 * w + 4 * qd + rx;
            Ow[base + ((size_t)t << 9) + et * 16 + l15] = (__bf16)(acc[rx] * inv[rx]);
        }
    }
}

// ---------------------------------------------------------------------------
// Output projection: same ring-4 counted-vmcnt template as k_qkv.
// Per n: GEMM M=1536 x E=512 x K=512. Grid 6m x 2e x 64n = 768 blocks.
__launch_bounds__(512, 2)
__global__ void k_proj(const __bf16* __restrict__ Ow, const __bf16* __restrict__ WpE,
                       const float* __restrict__ bp, float* __restrict__ out) {
    // XCD-contiguous bijective swizzle: 768 blocks = 8 XCDs * 96.
    const int g   = blockIdx.x;
    const int s   = (g & 7) * 96 + (g >> 3);
    const int n   = s / 12;
    const int r12 = s - n * 12;
    const int mx  = r12 >> 1;
    const int ey  = r12 & 1;
    const int m0  = mx * 256;
    const int e0  = ey * 256;

    __shared__ __align__(16) __bf16 Ar[4][256 * 32];
    __shared__ __align__(16) __bf16 Br[4][256 * 32];

    const int tid  = threadIdx.x;
    const int lane = tid & 63;
    const int w    = tid >> 6;
    const int wm2  = w >> 2;
    const int wn4  = w & 3;
    const int l15  = lane & 15, qd = lane >> 4;

    const int sr  = tid >> 2;
    const int sp  = tid & 3;
    const int sch = (sp ^ ((sr >> 1) & 3)) * 8;
    int mA0 = m0 + sr;       int bb0 = mA0 / 192, tt0 = mA0 - bb0 * 192;
    int mA1 = m0 + 128 + sr; int bb1 = mA1 / 192, tt1 = mA1 - bb1 * 192;
    const __bf16* aG0 = Ow + (((size_t)(bb0 * 64 + n) * 192 + tt0) << 9) + sch;
    const __bf16* aG1 = Ow + (((size_t)(bb1 * 64 + n) * 192 + tt1) << 9) + sch;
    const __bf16* bG0 = WpE + ((size_t)(e0 + sr) << 9) + sch;
    const __bf16* bG1 = bG0 + ((size_t)128 << 9);

    const int cro   = (qd ^ ((l15 >> 1) & 3)) * 8;
    const int arow0 = (wm2 * 128 + l15) * 32;
    const int brow0 = (wn4 * 64 + l15) * 32;

    f32x4 acc[8][4];
#pragma unroll
    for (int i = 0; i < 8; ++i)
#pragma unroll
        for (int j = 0; j < 4; ++j) acc[i][j] = (f32x4){0.f, 0.f, 0.f, 0.f};

    auto issue = [&](int t) {
        const int slot = t & 3;
        const int k0 = t * 32;
        __bf16* ad = &Ar[slot][tid * 8];
        __bf16* bd = &Br[slot][tid * 8];
        async16(aG0 + k0, ad);
        async16(aG1 + k0, ad + 4096);
        async16(bG0 + k0, bd);
        async16(bG1 + k0, bd + 4096);
    };
    auto compute = [&](int slot) {
        const __bf16* Asl = Ar[slot];
        const __bf16* Bsl = Br[slot];
        bf16x8 bfr[4], af[8];
#pragma unroll
        for (int j = 0; j < 4; ++j)
            bfr[j] = *(const bf16x8*)&Bsl[brow0 + j * 512 + cro];
#pragma unroll
        for (int i = 0; i < 8; ++i)
            af[i] = *(const bf16x8*)&Asl[arow0 + i * 512 + cro];
        __builtin_amdgcn_s_setprio(1);
#pragma unroll
        for (int i = 0; i < 8; ++i)
#pragma unroll
            for (int j = 0; j < 4; ++j)
                acc[i][j] = MFMA16(af[i], bfr[j], acc[i][j]);
        __builtin_amdgcn_s_setprio(0);
    };

    issue(0); issue(1); issue(2);
    asm volatile("s_waitcnt vmcnt(8)" ::: "memory");
    __builtin_amdgcn_s_barrier();

    for (int t = 0; t < 13; ++t) {
        issue(t + 3);
        compute(t & 3);
        asm volatile("s_waitcnt vmcnt(8)" ::: "memory");
        __builtin_amdgcn_s_barrier();
    }
    compute(1);
    asm volatile("s_waitcnt vmcnt(4)" ::: "memory");
    __builtin_amdgcn_s_barrier();
    compute(2);
    asm volatile("s_waitcnt vmcnt(0)" ::: "memory");
    __builtin_amdgcn_s_barrier();
    compute(3);

    float bias[4];
#pragma unroll
    for (int j = 0; j < 4; ++j) bias[j] = bp[e0 + wn4 * 64 + j * 16 + l15];
#pragma unroll
    for (int i = 0; i < 8; ++i) {
#pragma unroll
        for (int rx = 0; rx < 4; ++rx) {
            int m = m0 + wm2 * 128 + i * 16 + qd * 4 + rx;
            size_t ro = ((size_t)(m * 64 + n)) << 9;
#pragma unroll
            for (int j = 0; j < 4; ++j) {
                int e = e0 + wn4 * 64 + j * 16 + l15;
                out[ro + e] = acc[i][j][rx] + bias[j];
            }
        }
    }
}

// ---------------------------------------------------------------------------
extern "C" void kernel_launch(void* const* d_in, const int* in_sizes, int n_in,
                              void* d_out, int out_size, void* d_ws, size_t ws_size,
                              hipStream_t stream) {
    const float* x    = (const float*)d_in[0];
    const float* Wq_w = (const float*)d_in[1];
    const float* Wq_b = (const float*)d_in[2];
    const float* Wv_w = (const float*)d_in[3];
    const float* Wv_b = (const float*)d_in[4];
    const float* Wk   = (const float*)d_in[5];
    const float* bk   = (const float*)d_in[6];
    const float* Wp   = (const float*)d_in[7];
    const float* bp   = (const float*)d_in[8];
    const int*   cid  = (const int*)d_in[9];
    float* out = (float*)d_out;

    __bf16* WqE = (__bf16*)d_ws;
    __bf16* WvE = WqE + (1 << 18);
    __bf16* WpE = WvE + (1 << 18);
    __bf16* WkE = WpE + (1 << 18);
    __bf16* Qw  = WkE + (8 << 18);
    __bf16* Kw  = Qw + 50331648LL;
    __bf16* Vw  = Kw + 50331648LL;
    __bf16* XO  = Vw + 50331648LL;  // xbf during projections, Ow after attn

    k_cast3<<<1024, 256, 0, stream>>>(Wq_w, Wv_w, Wp, WqE, WvE, WpE);
    k_twk<<<8192, 256, 0, stream>>>(Wk, WkE);
    k_castx<<<24576, 256, 0, stream>>>(x, XO);
    k_qkv<<<dim3(36, 64), 512, 0, stream>>>(XO, WqE, WvE, WkE, Wq_b, Wv_b, bk, cid,
                                            Qw, Kw, Vw);
    k_attn<<<dim3(8, 64, 8), 768, 0, stream>>>(Qw, Kw, Vw, XO);
    k_proj<<<768, 512, 0, stream>>>(XO, WpE, bp, out);
}

// Round 4
// 754.238 us; speedup vs baseline: 1.1429x; 1.0389x over previous
//
#include <hip/hip_runtime.h>
#include <hip/hip_bf16.h>

typedef __bf16 bf16x8 __attribute__((ext_vector_type(8)));
typedef float  f32x4  __attribute__((ext_vector_type(4)));
typedef short  s16x4  __attribute__((ext_vector_type(4)));

#define MFMA16(a, b, c) __builtin_amdgcn_mfma_f32_16x16x32_bf16(a, b, c, 0, 0, 0)
#define MFMA16K16(a, b, c) __builtin_amdgcn_mfma_f32_16x16x16bf16_1k(a, b, c, 0, 0, 0)

// async global->LDS, 16 B per lane. LDS dest is wave-uniform base + lane*16;
// the GLOBAL address is per-lane free — we exploit that for the XOR swizzle.
__device__ __forceinline__ void async16(const __bf16* g, __bf16* l) {
    __builtin_amdgcn_global_load_lds(
        (const __attribute__((address_space(1))) unsigned int*)g,
        (__attribute__((address_space(3))) unsigned int*)l, 16, 0, 0);
}

// B=8 T=192 N=64 D=512 H=8 DH=64 C=8 ; per-n GEMM rows M = B*T = 1536

// ---------------------------------------------------------------------------
__global__ void k_cast3(const float* __restrict__ wq, const float* __restrict__ wv,
                        const float* __restrict__ wp,
                        __bf16* __restrict__ oq, __bf16* __restrict__ ov,
                        __bf16* __restrict__ op) {
    int i = blockIdx.x * 256 + threadIdx.x;
    oq[i] = (__bf16)wq[i];
    ov[i] = (__bf16)wv[i];
    op[i] = (__bf16)wp[i];
}

// Wk [c][d][e] fp32 -> bf16 [c][e][d], LDS-tiled transpose (coalesced both sides).
__global__ void k_twk(const float* __restrict__ wk, __bf16* __restrict__ o) {
    const int blk = blockIdx.x;         // 512 blocks = 8c * 8dt * 8et
    const int c  = blk >> 6;
    const int dt = (blk >> 3) & 7;
    const int et = blk & 7;
    __shared__ __bf16 T[64][72];        // +8 pad
    const int tid = threadIdx.x;        // 256
    {
        const int rd = tid >> 2;            // d row 0..63
        const int ce = (tid & 3) * 16;      // e col base
        const float* src = wk + ((size_t)c << 18) + ((size_t)(dt * 64 + rd) << 9)
                         + et * 64 + ce;
#pragma unroll
        for (int q = 0; q < 4; ++q) {
            float4 f = *(const float4*)(src + q * 4);
            T[rd][ce + q * 4 + 0] = (__bf16)f.x;
            T[rd][ce + q * 4 + 1] = (__bf16)f.y;
            T[rd][ce + q * 4 + 2] = (__bf16)f.z;
            T[rd][ce + q * 4 + 3] = (__bf16)f.w;
        }
    }
    __syncthreads();
    {
        const int re = tid >> 2;            // e row 0..63
        const int cd = (tid & 3) * 16;      // d col base
        bf16x8 v0, v1;
#pragma unroll
        for (int j = 0; j < 8; ++j) { v0[j] = T[cd + j][re]; v1[j] = T[cd + 8 + j][re]; }
        __bf16* dst = o + ((size_t)c << 18) + ((size_t)(et * 64 + re) << 9) + dt * 64 + cd;
        *(bf16x8*)dst = v0;
        *(bf16x8*)(dst + 8) = v1;
    }
}

// x fp32 [B,T,N,D] -> bf16 same layout
__global__ void k_castx(const float* __restrict__ x, __bf16* __restrict__ o) {
    size_t i = ((size_t)blockIdx.x * 256 + threadIdx.x) * 8;
    float4 f0 = *(const float4*)(x + i);
    float4 f1 = *(const float4*)(x + i + 4);
    bf16x8 v;
    v[0] = (__bf16)f0.x; v[1] = (__bf16)f0.y; v[2] = (__bf16)f0.z; v[3] = (__bf16)f0.w;
    v[4] = (__bf16)f1.x; v[5] = (__bf16)f1.y; v[6] = (__bf16)f1.z; v[7] = (__bf16)f1.w;
    *(bf16x8*)(o + i) = v;
}

// ---------------------------------------------------------------------------
// Fused QKV projection, 4-deep ring pipeline with COUNTED vmcnt (T3+T4+T5).
// (unchanged from round 3 — 219 us, MfmaUtil 30, conflicts 0)
__launch_bounds__(512, 2)
__global__ void k_qkv(const __bf16* __restrict__ xb,
                      const __bf16* __restrict__ WqE, const __bf16* __restrict__ WvE,
                      const __bf16* __restrict__ WkE,
                      const float* __restrict__ bq, const float* __restrict__ bv,
                      const float* __restrict__ bk, const int* __restrict__ cid,
                      __bf16* __restrict__ Qw, __bf16* __restrict__ Kw,
                      __bf16* __restrict__ Vw) {
    const int g   = blockIdx.y * 36 + blockIdx.x;
    const int s   = (g & 7) * 288 + (g >> 3);
    const int n   = s / 36;
    const int r36 = s - n * 36;
    const int mx  = r36 / 6;
    const int ey  = r36 - mx * 6;
    const int m0  = mx * 256;
    const int e0  = ey * 256;
    const int seg  = e0 >> 9;      // 0=Q 1=V 2=K
    const int eoff = e0 & 511;     // 0 or 256
    const int c    = cid[n];

    const __bf16* Wb = (seg == 0) ? WqE : (seg == 1) ? WvE : (WkE + ((size_t)c << 18));
    __bf16*       Ob = (seg == 0) ? Qw : (seg == 1) ? Vw : Kw;

    __shared__ __align__(16) __bf16 Ar[4][256 * 32];
    __shared__ __align__(16) __bf16 Br[4][256 * 32];

    const int tid  = threadIdx.x;
    const int lane = tid & 63;
    const int w    = tid >> 6;
    const int wm2  = w >> 2;
    const int wn4  = w & 3;
    const int l15  = lane & 15, qd = lane >> 4;

    const int sr  = tid >> 2;
    const int sp  = tid & 3;
    const int sch = (sp ^ ((sr >> 1) & 3)) * 8;
    const __bf16* aG0 = xb + ((size_t)(m0 + sr) * 64 + n) * 512 + sch;
    const __bf16* aG1 = aG0 + (size_t)128 * 64 * 512;
    const __bf16* bG0 = Wb + ((size_t)(eoff + sr) << 9) + sch;
    const __bf16* bG1 = bG0 + ((size_t)128 << 9);

    const int cro   = (qd ^ ((l15 >> 1) & 3)) * 8;
    const int arow0 = (wm2 * 128 + l15) * 32;
    const int brow0 = (wn4 * 64 + l15) * 32;

    f32x4 acc[8][4];
#pragma unroll
    for (int i = 0; i < 8; ++i)
#pragma unroll
        for (int j = 0; j < 4; ++j) acc[i][j] = (f32x4){0.f, 0.f, 0.f, 0.f};

    auto issue = [&](int t) {
        const int slot = t & 3;
        const int k0 = t * 32;
        __bf16* ad = &Ar[slot][tid * 8];
        __bf16* bd = &Br[slot][tid * 8];
        async16(aG0 + k0, ad);
        async16(aG1 + k0, ad + 4096);
        async16(bG0 + k0, bd);
        async16(bG1 + k0, bd + 4096);
    };
    auto compute = [&](int slot) {
        const __bf16* Asl = Ar[slot];
        const __bf16* Bsl = Br[slot];
        bf16x8 bfr[4], af[8];
#pragma unroll
        for (int j = 0; j < 4; ++j)
            bfr[j] = *(const bf16x8*)&Bsl[brow0 + j * 512 + cro];
#pragma unroll
        for (int i = 0; i < 8; ++i)
            af[i] = *(const bf16x8*)&Asl[arow0 + i * 512 + cro];
        __builtin_amdgcn_s_setprio(1);
#pragma unroll
        for (int i = 0; i < 8; ++i)
#pragma unroll
            for (int j = 0; j < 4; ++j)
                acc[i][j] = MFMA16(af[i], bfr[j], acc[i][j]);
        __builtin_amdgcn_s_setprio(0);
    };

    issue(0); issue(1); issue(2);
    asm volatile("s_waitcnt vmcnt(8)" ::: "memory");
    __builtin_amdgcn_s_barrier();

    for (int t = 0; t < 13; ++t) {
        issue(t + 3);
        compute(t & 3);
        asm volatile("s_waitcnt vmcnt(8)" ::: "memory");
        __builtin_amdgcn_s_barrier();
    }
    compute(1);
    asm volatile("s_waitcnt vmcnt(4)" ::: "memory");
    __builtin_amdgcn_s_barrier();
    compute(2);
    asm volatile("s_waitcnt vmcnt(0)" ::: "memory");
    __builtin_amdgcn_s_barrier();
    compute(3);

    float bias[4];
#pragma unroll
    for (int j = 0; j < 4; ++j) {
        int e = eoff + wn4 * 64 + j * 16 + l15;
        bias[j] = (seg == 0) ? bq[e] : (seg == 1) ? bv[e] : bk[(c << 9) + e];
    }
#pragma unroll
    for (int i = 0; i < 8; ++i) {
#pragma unroll
        for (int rx = 0; rx < 4; ++rx) {
            int m  = m0 + wm2 * 128 + i * 16 + qd * 4 + rx;
            int bb = m / 192;
            int tt = m - bb * 192;
            size_t ro = ((size_t)(bb * 64 + n) * 192 + tt) << 9;
#pragma unroll
            for (int j = 0; j < 4; ++j) {
                int e = eoff + wn4 * 64 + j * 16 + l15;
                Ob[ro + e] = (__bf16)(acc[i][j][rx] + bias[j]);
            }
        }
    }
}

// ---------------------------------------------------------------------------
// Attention, one (b,n,h) per block; 12 waves each own one 16-row Q strip.
// SWAPPED QK^T: S = mfma(K_frag, Q_frag) -> lane holds t=l15 (col), s=16ct+qd*4+rx
// (row-regs). Softmax row-reduce = 2 shfl_xor (16,32). P packed to bf16 pairs
// via v_cvt_pk_bf16_f32 is EXACTLY the 16x16x16 A-fragment (k=qd*4+{0..3}) for
// PV -> no P LDS round-trip, no mid barrier. Ps buffer deleted: LDS 52 KB.
__launch_bounds__(768)
__global__ void k_attn(const __bf16* __restrict__ Qw, const __bf16* __restrict__ Kw,
                       const __bf16* __restrict__ Vw, __bf16* __restrict__ Ow) {
    const int h = blockIdx.x, n = blockIdx.y, b = blockIdx.z;
    __shared__ __align__(16) __bf16 Ks[192 * 72];   // [s][k] 27.6 KB
    __shared__ __align__(16) __bf16 Vt[64 * 192];   // [e][s] chunk-swizzled 24.6 KB

    const int tid  = threadIdx.x;
    const int lane = tid & 63, w = tid >> 6;
    const int l15  = lane & 15, qd = lane >> 4;
    const size_t base = ((size_t)((b * 64 + n) * 192) << 9) + h * 64;

    for (int i = tid; i < 1536; i += 768) {  // K rows, b128
        int row = i >> 3, pp = i & 7;
        *(bf16x8*)&Ks[row * 72 + 8 * pp] =
            *(const bf16x8*)(Kw + base + ((size_t)row << 9) + 8 * pp);
    }
    // V^T: column gather (coalesced 128B reads) + one swizzled b128 write.
    // Vt[e][s-chunk c] stored at chunk position c ^ (e&7), row stride 192 elems.
#pragma unroll
    for (int rr = 0; rr < 2; ++rr) {
        int idx = rr * 768 + tid;          // 0..1535
        int e = idx & 63, sb = idx >> 6;   // sb 0..23
        bf16x8 v;
#pragma unroll
        for (int j = 0; j < 8; ++j)
            v[j] = Vw[base + (size_t)(sb * 8 + j) * 512 + e];
        *(bf16x8*)&Vt[e * 192 + ((sb ^ (e & 7)) * 8)] = v;
    }
    __syncthreads();

    const __bf16* qp = Qw + base + ((size_t)(16 * w + l15) << 9) + 8 * qd;
    bf16x8 aq0 = *(const bf16x8*)(qp);
    bf16x8 aq1 = *(const bf16x8*)(qp + 32);

    f32x4 S[12];
#pragma unroll
    for (int ct = 0; ct < 12; ++ct) {
        f32x4 acc = (f32x4){0.f, 0.f, 0.f, 0.f};
        bf16x8 b0 = *(const bf16x8*)&Ks[(16 * ct + l15) * 72 + 8 * qd];
        bf16x8 b1 = *(const bf16x8*)&Ks[(16 * ct + l15) * 72 + 32 + 8 * qd];
        acc = MFMA16(b0, aq0, acc);   // swapped: A=K rows s, B=Q rows t
        acc = MFMA16(b1, aq1, acc);
        S[ct] = acc;
    }

    float mx = -1e30f;
#pragma unroll
    for (int ct = 0; ct < 12; ++ct)
#pragma unroll
        for (int rx = 0; rx < 4; ++rx) mx = fmaxf(mx, S[ct][rx]);
    mx = fmaxf(mx, __shfl_xor(mx, 16, 64));
    mx = fmaxf(mx, __shfl_xor(mx, 32, 64));

    const float sc = 0.125f * 1.44269504088896f;
    float sm = 0.f;
#pragma unroll
    for (int ct = 0; ct < 12; ++ct)
#pragma unroll
        for (int rx = 0; rx < 4; ++rx) {
            float pe = exp2f((S[ct][rx] - mx) * sc);
            S[ct][rx] = pe;
            sm += pe;
        }
    sm += __shfl_xor(sm, 16, 64);
    sm += __shfl_xor(sm, 32, 64);
    const float inv = 1.f / sm;      // for row t = 16w + l15

    // pack P to bf16: pk0 = s{+0,+1}, pk1 = s{+2,+3} at s = 16ct + qd*4
    unsigned pk0[12], pk1[12];
#pragma unroll
    for (int ct = 0; ct < 12; ++ct) {
        asm("v_cvt_pk_bf16_f32 %0, %1, %2" : "=v"(pk0[ct]) : "v"(S[ct][0]), "v"(S[ct][1]));
        asm("v_cvt_pk_bf16_f32 %0, %1, %2" : "=v"(pk1[ct]) : "v"(S[ct][2]), "v"(S[ct][3]));
    }

    // gather 1/sum for this lane's output rows t = 16w + qd*4 + rx
    float invr[4];
#pragma unroll
    for (int rx = 0; rx < 4; ++rx) invr[rx] = __shfl(inv, qd * 4 + rx, 64);

    // PV with 16x16x16 MFMAs: A = P rows t (lane-local!), B = V^T rows e.
#pragma unroll
    for (int et = 0; et < 4; ++et) {
        f32x4 acc = (f32x4){0.f, 0.f, 0.f, 0.f};
#pragma unroll
        for (int sn = 0; sn < 12; ++sn) {
            union { unsigned u[2]; s16x4 s; } pa;
            pa.u[0] = pk0[sn];
            pa.u[1] = pk1[sn];
            const int sb = sn * 2 + (qd >> 1);          // 8-elem chunk of s
            s16x4 vb = *(const s16x4*)
                &Vt[(et * 16 + l15) * 192 + ((sb ^ (l15 & 7)) * 8) + (qd & 1) * 4];
            acc = MFMA16K16(pa.s, vb, acc);
        }
#pragma unroll
        for (int rx = 0; rx < 4; ++rx) {
            int t = 16 * w + 4 * qd + rx;
            Ow[base + ((size_t)t << 9) + et * 16 + l15] = (__bf16)(acc[rx] * invr[rx]);
        }
    }
}

// ---------------------------------------------------------------------------
// Output projection: same ring-4 counted-vmcnt template as k_qkv.
__launch_bounds__(512, 2)
__global__ void k_proj(const __bf16* __restrict__ Ow, const __bf16* __restrict__ WpE,
                       const float* __restrict__ bp, float* __restrict__ out) {
    const int g   = blockIdx.x;
    const int s   = (g & 7) * 96 + (g >> 3);
    const int n   = s / 12;
    const int r12 = s - n * 12;
    const int mx  = r12 >> 1;
    const int ey  = r12 & 1;
    const int m0  = mx * 256;
    const int e0  = ey * 256;

    __shared__ __align__(16) __bf16 Ar[4][256 * 32];
    __shared__ __align__(16) __bf16 Br[4][256 * 32];

    const int tid  = threadIdx.x;
    const int lane = tid & 63;
    const int w    = tid >> 6;
    const int wm2  = w >> 2;
    const int wn4  = w & 3;
    const int l15  = lane & 15, qd = lane >> 4;

    const int sr  = tid >> 2;
    const int sp  = tid & 3;
    const int sch = (sp ^ ((sr >> 1) & 3)) * 8;
    int mA0 = m0 + sr;       int bb0 = mA0 / 192, tt0 = mA0 - bb0 * 192;
    int mA1 = m0 + 128 + sr; int bb1 = mA1 / 192, tt1 = mA1 - bb1 * 192;
    const __bf16* aG0 = Ow + (((size_t)(bb0 * 64 + n) * 192 + tt0) << 9) + sch;
    const __bf16* aG1 = Ow + (((size_t)(bb1 * 64 + n) * 192 + tt1) << 9) + sch;
    const __bf16* bG0 = WpE + ((size_t)(e0 + sr) << 9) + sch;
    const __bf16* bG1 = bG0 + ((size_t)128 << 9);

    const int cro   = (qd ^ ((l15 >> 1) & 3)) * 8;
    const int arow0 = (wm2 * 128 + l15) * 32;
    const int brow0 = (wn4 * 64 + l15) * 32;

    f32x4 acc[8][4];
#pragma unroll
    for (int i = 0; i < 8; ++i)
#pragma unroll
        for (int j = 0; j < 4; ++j) acc[i][j] = (f32x4){0.f, 0.f, 0.f, 0.f};

    auto issue = [&](int t) {
        const int slot = t & 3;
        const int k0 = t * 32;
        __bf16* ad = &Ar[slot][tid * 8];
        __bf16* bd = &Br[slot][tid * 8];
        async16(aG0 + k0, ad);
        async16(aG1 + k0, ad + 4096);
        async16(bG0 + k0, bd);
        async16(bG1 + k0, bd + 4096);
    };
    auto compute = [&](int slot) {
        const __bf16* Asl = Ar[slot];
        const __bf16* Bsl = Br[slot];
        bf16x8 bfr[4], af[8];
#pragma unroll
        for (int j = 0; j < 4; ++j)
            bfr[j] = *(const bf16x8*)&Bsl[brow0 + j * 512 + cro];
#pragma unroll
        for (int i = 0; i < 8; ++i)
            af[i] = *(const bf16x8*)&Asl[arow0 + i * 512 + cro];
        __builtin_amdgcn_s_setprio(1);
#pragma unroll
        for (int i = 0; i < 8; ++i)
#pragma unroll
            for (int j = 0; j < 4; ++j)
                acc[i][j] = MFMA16(af[i], bfr[j], acc[i][j]);
        __builtin_amdgcn_s_setprio(0);
    };

    issue(0); issue(1); issue(2);
    asm volatile("s_waitcnt vmcnt(8)" ::: "memory");
    __builtin_amdgcn_s_barrier();

    for (int t = 0; t < 13; ++t) {
        issue(t + 3);
        compute(t & 3);
        asm volatile("s_waitcnt vmcnt(8)" ::: "memory");
        __builtin_amdgcn_s_barrier();
    }
    compute(1);
    asm volatile("s_waitcnt vmcnt(4)" ::: "memory");
    __builtin_amdgcn_s_barrier();
    compute(2);
    asm volatile("s_waitcnt vmcnt(0)" ::: "memory");
    __builtin_amdgcn_s_barrier();
    compute(3);

    float bias[4];
#pragma unroll
    for (int j = 0; j < 4; ++j) bias[j] = bp[e0 + wn4 * 64 + j * 16 + l15];
#pragma unroll
    for (int i = 0; i < 8; ++i) {
#pragma unroll
        for (int rx = 0; rx < 4; ++rx) {
            int m = m0 + wm2 * 128 + i * 16 + qd * 4 + rx;
            size_t ro = ((size_t)(m * 64 + n)) << 9;
#pragma unroll
            for (int j = 0; j < 4; ++j) {
                int e = e0 + wn4 * 64 + j * 16 + l15;
                out[ro + e] = acc[i][j][rx] + bias[j];
            }
        }
    }
}

// ---------------------------------------------------------------------------
extern "C" void kernel_launch(void* const* d_in, const int* in_sizes, int n_in,
                              void* d_out, int out_size, void* d_ws, size_t ws_size,
                              hipStream_t stream) {
    const float* x    = (const float*)d_in[0];
    const float* Wq_w = (const float*)d_in[1];
    const float* Wq_b = (const float*)d_in[2];
    const float* Wv_w = (const float*)d_in[3];
    const float* Wv_b = (const float*)d_in[4];
    const float* Wk   = (const float*)d_in[5];
    const float* bk   = (const float*)d_in[6];
    const float* Wp   = (const float*)d_in[7];
    const float* bp   = (const float*)d_in[8];
    const int*   cid  = (const int*)d_in[9];
    float* out = (float*)d_out;

    __bf16* WqE = (__bf16*)d_ws;
    __bf16* WvE = WqE + (1 << 18);
    __bf16* WpE = WvE + (1 << 18);
    __bf16* WkE = WpE + (1 << 18);
    __bf16* Qw  = WkE + (8 << 18);
    __bf16* Kw  = Qw + 50331648LL;
    __bf16* Vw  = Kw + 50331648LL;
    __bf16* XO  = Vw + 50331648LL;  // xbf during projections, Ow after attn

    k_cast3<<<1024, 256, 0, stream>>>(Wq_w, Wv_w, Wp, WqE, WvE, WpE);
    k_twk<<<512, 256, 0, stream>>>(Wk, WkE);
    k_castx<<<24576, 256, 0, stream>>>(x, XO);
    k_qkv<<<dim3(36, 64), 512, 0, stream>>>(XO, WqE, WvE, WkE, Wq_b, Wv_b, bk, cid,
                                            Qw, Kw, Vw);
    k_attn<<<dim3(8, 64, 8), 768, 0, stream>>>(Qw, Kw, Vw, XO);
    k_proj<<<768, 512, 0, stream>>>(XO, WpE, bp, out);
}